// Round 7
// baseline (420.367 us; speedup 1.0000x reference)
//
#include <hip/hip_runtime.h>

#define NB 128
#define T_DIM 50
#define Q_DIM 1024
#define H_DIM 256
#define S_DIM 49                 // MAX_STEP - 1
#define K_DIM 51200              // T*Q
#define KCHUNKS 80
#define KC 640                   // K per chunk
#define BK 64                    // K per LDS stage
#define NSTAGE 10                // KC/BK
#define GRAM_N (NB * NB)         // 16384
#define LROWU 36                 // uints per padded LDS row (64 f16 + 8 pad)
#define CPAD 132                 // padded f32 row for sinkhorn cost matrix
#define NTILE 800                // K_DIM / BK
#define TSTRU 4160               // uints per tile: 128*32 data + 32 pad (16640 B, !=0 mod 8192)

typedef __attribute__((ext_vector_type(4))) float f32x4;
typedef __attribute__((ext_vector_type(8))) _Float16 half8v;
typedef __attribute__((ext_vector_type(4))) unsigned int uint4v;
typedef __attribute__((ext_vector_type(2))) unsigned int uint2v;
using pk2_t = decltype(__builtin_amdgcn_cvt_pkrtz(0.0f, 0.0f));

union PKU { pk2_t p; unsigned int u; };
union U4H8 { uint4v u; half8v h; };

__device__ inline unsigned short f2bf_rn(float x) {   // round-nearest-even bf16
  union { float f; unsigned int u; } v; v.f = x;
  unsigned int r = v.u + 0x7FFFu + ((v.u >> 16) & 1u);
  return (unsigned short)(r >> 16);
}
__device__ inline float bf2f(unsigned short b) {
  union { float f; unsigned int u; } v; v.u = ((unsigned int)b) << 16;
  return v.f;
}

// ---------------------------------------------------------------------------
// Kernel 0: streaming f32 -> f16 tile conversion.  (RESUBMISSION of round-6:
// prior bench died at the container level with no kernel signal; OOB/align/
// workspace audits clean — see session log.)
// Theory: the gram kernel's staging reads (128 rows x 256B at one K-offset,
// row stride 204800B == 0 mod 8192) collapse onto a single DRAM-channel
// offset per stage -> HBM pinned at ~1.4 TB/s in ALL five prior variants
// regardless of occupancy/schedule. This pass reads each row SEQUENTIALLY
// (204.8KB sweeps -> all channels, streaming rate), converts with the SAME
// RTZ cvt_pkrtz, and writes tiles [w][row][64 f16] with stride 16640B
// (!= 0 mod 8192 -> writes spread channels; 79.9MB, L3-resident).
// grid = (6 matrices x 128 rows), block = 256. Bit-identical data to what
// the old kernel staged into LDS.
// ---------------------------------------------------------------------------
__global__ __launch_bounds__(256) void convert_kernel(
    const float* __restrict__ s0, const float* __restrict__ s1, const float* __restrict__ s2,
    const float* __restrict__ t0, const float* __restrict__ t1, const float* __restrict__ t2,
    unsigned int* __restrict__ tiles) {
  const int m = blockIdx.x >> 7;       // 0..5
  const int r = blockIdx.x & 127;      // row
  const float* src = (m == 0) ? s0 : (m == 1) ? s1 : (m == 2) ? s2
                   : (m == 3) ? t0 : (m == 4) ? t1 : t2;
  const float* row = src + (size_t)r * K_DIM;
  unsigned int* base = tiles + (size_t)m * NTILE * TSTRU;
  const int t = threadIdx.x;
#pragma unroll
  for (int i = 0; i < 4; i++) {
    const int w = i * 256 + t;         // tile index 0..799
    if (w < NTILE) {
      const float* pk = row + w * 64;                  // 256B contiguous read
      unsigned int* dst = base + (size_t)w * TSTRU + r * 32;  // 128B row slot
#pragma unroll
      for (int j = 0; j < 8; j++) {
        const f32x4 a = *(const f32x4*)(pk + j * 8);
        const f32x4 b = *(const f32x4*)(pk + j * 8 + 4);
        PKU u0, u1, u2, u3;
        u0.p = __builtin_amdgcn_cvt_pkrtz(a[0], a[1]);
        u1.p = __builtin_amdgcn_cvt_pkrtz(a[2], a[3]);
        u2.p = __builtin_amdgcn_cvt_pkrtz(b[0], b[1]);
        u3.p = __builtin_amdgcn_cvt_pkrtz(b[2], b[3]);
        uint4v wv; wv.x = u0.u; wv.y = u1.u; wv.z = u2.u; wv.w = u3.u;
        *(uint4v*)(dst + j * 4) = wv;
      }
    }
  }
}

// ---------------------------------------------------------------------------
// shared compute helper (16-wave fused tile, verified rounds 0/3/4)
// ---------------------------------------------------------------------------
__device__ __forceinline__ void compute_stage(
    const unsigned int* __restrict__ panA, const unsigned int* __restrict__ panB,
    int wrow, int wcol, int l15, int quad,
    f32x4 (&aXY)[2][2], f32x4 (&aXX)[2][2], f32x4 (&aYY)[2][2]) {
#pragma unroll
  for (int ks = 0; ks < 2; ks++) {
    const int kc = ks * 16 + quad * 4;
    half8v as_[2], bs_[2], at_[2], bt_[2];
#pragma unroll
    for (int t = 0; t < 2; t++) {
      U4H8 u;
      u.u = *(const uint4v*)&panA[(wrow * 32 + t * 16 + l15) * LROWU + kc]; as_[t] = u.h;
      u.u = *(const uint4v*)&panA[(wcol * 32 + t * 16 + l15) * LROWU + kc]; bs_[t] = u.h;
      u.u = *(const uint4v*)&panB[(wrow * 32 + t * 16 + l15) * LROWU + kc]; at_[t] = u.h;
      u.u = *(const uint4v*)&panB[(wcol * 32 + t * 16 + l15) * LROWU + kc]; bt_[t] = u.h;
    }
#pragma unroll
    for (int ti = 0; ti < 2; ti++)
#pragma unroll
      for (int tj = 0; tj < 2; tj++) {
        aXY[ti][tj] = __builtin_amdgcn_mfma_f32_16x16x32_f16(as_[ti], bt_[tj], aXY[ti][tj], 0, 0, 0);
        aXX[ti][tj] = __builtin_amdgcn_mfma_f32_16x16x32_f16(as_[ti], bs_[tj], aXX[ti][tj], 0, 0, 0);
        aYY[ti][tj] = __builtin_amdgcn_mfma_f32_16x16x32_f16(at_[ti], bt_[tj], aYY[ti][tj], 0, 0, 0);
      }
  }
}

// ---------------------------------------------------------------------------
// Kernel 1: gram from f16 tiles. grid = (KCHUNKS, 3), block = 1024.
// Staging is ONE uint4v (16B) per panel per thread from a CONTIGUOUS 16KB
// tile (lane-consecutive 16B -> perfect coalescing, L3-served, no cvt).
// K-window mapping w = chunk*10+st identical to the f32 path -> MFMA slice
// composition, accumulation order, bf16 partials all bit-identical.
// Schedule = round-3 proven 1-barrier dbuf.
// ---------------------------------------------------------------------------
__global__ __launch_bounds__(1024) void gram_tiles_kernel(
    const unsigned int* __restrict__ tiles, unsigned short* __restrict__ part) {
  __shared__ unsigned int pan[2][2][NB * LROWU];   // 73728 B

  const int chunk = blockIdx.x;
  const int pair = blockIdx.y;
  const unsigned int* tS = tiles + (size_t)pair * NTILE * TSTRU;
  const unsigned int* tT = tiles + (size_t)(pair + 3) * NTILE * TSTRU;

  const int tid = threadIdx.x;
  const int wave = tid >> 6, lane = tid & 63;
  const int wrow = wave >> 2, wcol = wave & 3;
  const int l15 = lane & 15, quad = lane >> 4;

  f32x4 aXY[2][2], aXX[2][2], aYY[2][2];
#pragma unroll
  for (int i = 0; i < 2; i++)
#pragma unroll
    for (int j = 0; j < 2; j++) {
      aXY[i][j] = (f32x4){0.f, 0.f, 0.f, 0.f};
      aXX[i][j] = (f32x4){0.f, 0.f, 0.f, 0.f};
      aYY[i][j] = (f32x4){0.f, 0.f, 0.f, 0.f};
    }

  const int r0 = tid >> 3;             // LDS row
  const int h  = tid & 7;              // 16B slot within row
  const size_t soff = (size_t)tid * 4; // uints within tile (== r0*32 + h*4)

  uint4v pS, pT;
#define ISSUE(ST)                                                     \
  {                                                                   \
    const size_t tb = (size_t)(chunk * NSTAGE + (ST)) * TSTRU;        \
    pS = *(const uint4v*)(tS + tb + soff);                            \
    pT = *(const uint4v*)(tT + tb + soff);                            \
  }
#define WRITE(BUF)                                                    \
  {                                                                   \
    *(uint4v*)&pan[BUF][0][r0 * LROWU + h * 4] = pS;                  \
    *(uint4v*)&pan[BUF][1][r0 * LROWU + h * 4] = pT;                  \
  }

  ISSUE(0)
  WRITE(0)
  __syncthreads();

  for (int st = 0; st < NSTAGE; st++) {
    const int buf = st & 1;
    if (st + 1 < NSTAGE) ISSUE(st + 1)                 // in flight across compute
    compute_stage(&pan[buf][0][0], &pan[buf][1][0], wrow, wcol, l15, quad, aXY, aXX, aYY);
    if (st + 1 < NSTAGE) {
      WRITE(buf ^ 1)
      __syncthreads();
    }
  }
#undef ISSUE
#undef WRITE

#pragma unroll
  for (int kind = 0; kind < 3; kind++) {
    unsigned short* out = part + ((size_t)(pair * 3 + kind) * KCHUNKS + chunk) * GRAM_N;
#pragma unroll
    for (int ti = 0; ti < 2; ti++)
#pragma unroll
      for (int tj = 0; tj < 2; tj++) {
        const f32x4 v = (kind == 0) ? aXY[ti][tj] : ((kind == 1) ? aXX[ti][tj] : aYY[ti][tj]);
        const int col = wcol * 32 + tj * 16 + l15;
#pragma unroll
        for (int r = 0; r < 4; r++) {
          const int row = wrow * 32 + ti * 16 + quad * 4 + r;
          out[(size_t)row * NB + col] = f2bf_rn(v[r]);
        }
      }
  }
}

// ---------------------------------------------------------------------------
// LEGACY gram (round-4 verified, 66.6us) — fallback when ws too small.
// ---------------------------------------------------------------------------
__device__ __forceinline__ void issue_loads(
    const float* __restrict__ S, const float* __restrict__ Tm,
    size_t ro0, size_t ro1, int kpos, int kq,
    f32x4& p0, f32x4& p1, f32x4& p2, f32x4& p3) {
  const float* pS = S + kpos + kq * 4;
  const float* pT = Tm + kpos + kq * 4;
  p0 = *(const f32x4*)(pS + ro0);
  p1 = *(const f32x4*)(pS + ro1);
  p2 = *(const f32x4*)(pT + ro0);
  p3 = *(const f32x4*)(pT + ro1);
}

__device__ __forceinline__ void cvt_write(
    unsigned int* __restrict__ panA, unsigned int* __restrict__ panB,
    int r0, int kq,
    const f32x4& p0, const f32x4& p1, const f32x4& p2, const f32x4& p3) {
  PKU a, b; uint2v w;
  a.p = __builtin_amdgcn_cvt_pkrtz(p0[0], p0[1]);
  b.p = __builtin_amdgcn_cvt_pkrtz(p0[2], p0[3]);
  w.x = a.u; w.y = b.u;
  *(uint2v*)&panA[r0 * LROWU + kq * 2] = w;
  a.p = __builtin_amdgcn_cvt_pkrtz(p1[0], p1[1]);
  b.p = __builtin_amdgcn_cvt_pkrtz(p1[2], p1[3]);
  w.x = a.u; w.y = b.u;
  *(uint2v*)&panA[(r0 + 64) * LROWU + kq * 2] = w;
  a.p = __builtin_amdgcn_cvt_pkrtz(p2[0], p2[1]);
  b.p = __builtin_amdgcn_cvt_pkrtz(p2[2], p2[3]);
  w.x = a.u; w.y = b.u;
  *(uint2v*)&panB[r0 * LROWU + kq * 2] = w;
  a.p = __builtin_amdgcn_cvt_pkrtz(p3[0], p3[1]);
  b.p = __builtin_amdgcn_cvt_pkrtz(p3[2], p3[3]);
  w.x = a.u; w.y = b.u;
  *(uint2v*)&panB[(r0 + 64) * LROWU + kq * 2] = w;
}

__global__ __launch_bounds__(1024) void gram_fused_legacy(
    const float* __restrict__ s0, const float* __restrict__ s1, const float* __restrict__ s2,
    const float* __restrict__ t0, const float* __restrict__ t1, const float* __restrict__ t2,
    unsigned short* __restrict__ part) {
  __shared__ unsigned int pan[2][2][NB * LROWU];

  const int chunk = blockIdx.x;
  const int pair = blockIdx.y;
  const float* S  = (pair == 0) ? s0 : ((pair == 1) ? s1 : s2);
  const float* Tm = (pair == 0) ? t0 : ((pair == 1) ? t1 : t2);

  const int tid = threadIdx.x;
  const int wave = tid >> 6, lane = tid & 63;
  const int wrow = wave >> 2, wcol = wave & 3;
  const int l15 = lane & 15, quad = lane >> 4;

  f32x4 aXY[2][2], aXX[2][2], aYY[2][2];
#pragma unroll
  for (int i = 0; i < 2; i++)
#pragma unroll
    for (int j = 0; j < 2; j++) {
      aXY[i][j] = (f32x4){0.f, 0.f, 0.f, 0.f};
      aXX[i][j] = (f32x4){0.f, 0.f, 0.f, 0.f};
      aYY[i][j] = (f32x4){0.f, 0.f, 0.f, 0.f};
    }

  const int r0 = tid >> 4;
  const int kq = tid & 15;
  const size_t ro0 = (size_t)r0 * K_DIM;
  const size_t ro1 = (size_t)(r0 + 64) * K_DIM;
  const int kbase = chunk * KC;

  f32x4 A0, A1, A2, A3, B0, B1, B2, B3;

  issue_loads(S, Tm, ro0, ro1, kbase, kq, A0, A1, A2, A3);
  issue_loads(S, Tm, ro0, ro1, kbase + BK, kq, B0, B1, B2, B3);
  cvt_write(&pan[0][0][0], &pan[0][1][0], r0, kq, A0, A1, A2, A3);
  __syncthreads();

  for (int s2 = 0; s2 < NSTAGE; s2 += 2) {
    if (s2 + 2 < NSTAGE)
      issue_loads(S, Tm, ro0, ro1, kbase + (s2 + 2) * BK, kq, A0, A1, A2, A3);
    compute_stage(&pan[0][0][0], &pan[0][1][0], wrow, wcol, l15, quad, aXY, aXX, aYY);
    cvt_write(&pan[1][0][0], &pan[1][1][0], r0, kq, B0, B1, B2, B3);
    __syncthreads();

    if (s2 + 3 < NSTAGE)
      issue_loads(S, Tm, ro0, ro1, kbase + (s2 + 3) * BK, kq, B0, B1, B2, B3);
    compute_stage(&pan[1][0][0], &pan[1][1][0], wrow, wcol, l15, quad, aXY, aXX, aYY);
    if (s2 + 2 < NSTAGE) {
      cvt_write(&pan[0][0][0], &pan[0][1][0], r0, kq, A0, A1, A2, A3);
      __syncthreads();
    }
  }

#pragma unroll
  for (int kind = 0; kind < 3; kind++) {
    unsigned short* out = part + ((size_t)(pair * 3 + kind) * KCHUNKS + chunk) * GRAM_N;
#pragma unroll
    for (int ti = 0; ti < 2; ti++)
#pragma unroll
      for (int tj = 0; tj < 2; tj++) {
        const f32x4 v = (kind == 0) ? aXY[ti][tj] : ((kind == 1) ? aXX[ti][tj] : aYY[ti][tj]);
        const int col = wcol * 32 + tj * 16 + l15;
#pragma unroll
        for (int r = 0; r < 4; r++) {
          const int row = wrow * 32 + ti * 16 + quad * 4 + r;
          out[(size_t)row * NB + col] = f2bf_rn(v[r]);
        }
      }
  }
}

// ---------------------------------------------------------------------------
// Kernel 2: reduce bf16 K-chunk partials -> gram[9][128][128] (f32)
// ---------------------------------------------------------------------------
__global__ __launch_bounds__(256) void gram_reduce_kernel(
    const unsigned short* __restrict__ part, float* __restrict__ gram) {
  const int idx = blockIdx.x * 256 + threadIdx.x;   // < 9*16384
  const int g = idx >> 14;
  const int cell = idx & (GRAM_N - 1);
  const unsigned short* p = part + (size_t)g * KCHUNKS * GRAM_N + cell;
  float s = 0.f;
#pragma unroll
  for (int c = 0; c < KCHUNKS; c++) s += bf2f(p[(size_t)c * GRAM_N]);
  gram[idx] = s;
}

// ---------------------------------------------------------------------------
// Kernel 3: Sinkhorn, per (pair, kind) chain. (unchanged — verified 5x)
// ---------------------------------------------------------------------------
__global__ __launch_bounds__(256, 1) void sinkhorn_part_kernel(
    const float* __restrict__ gram, float* __restrict__ kdpart) {
  const int pair = blockIdx.x, kind = blockIdx.y;
  const float* Gxy = gram + (size_t)(3 * pair + 0) * GRAM_N;
  const float* Gxx = gram + (size_t)(3 * pair + 1) * GRAM_N;
  const float* Gyy = gram + (size_t)(3 * pair + 2) * GRAM_N;

  __shared__ float CL[NB * CPAD];     // 67584 B, f32 cost matrix
  __shared__ f32x4 h4a[NB / 4];       // pot0 (f-side)
  __shared__ f32x4 h4b[NB / 4];       // pot1 (g-side, kind0 only)
  __shared__ float nx[NB], ny[NB];
  __shared__ float red[256];

  const int tid = threadIdx.x;
  if (tid < NB) {
    nx[tid] = Gxx[tid * (NB + 1)];
    ny[tid] = Gyy[tid * (NB + 1)];
    ((float*)h4a)[tid] = 0.f;
    ((float*)h4b)[tid] = 0.f;
  }
  __syncthreads();

  const float* G  = (kind == 0) ? Gxy : ((kind == 1) ? Gxx : Gyy);
  const float* rn = (kind == 2) ? ny : nx;
  const float* cn = (kind == 1) ? nx : ny;
  for (int idx = tid; idx < GRAM_N; idx += 256) {
    const int i = idx >> 7, j = idx & 127;
    CL[i * CPAD + j] = 2.0f * fmaxf(rn[i] + cn[j] - 2.0f * G[idx], 0.0f);
  }
  __syncthreads();

  const float rho = 250000.0f;
  const float AL = -4.852030263919617f;     // -log(128)
  const float LOG2E = 1.4426950408889634f;
  const float LN2 = 0.6931471805599453f;
  const int grp = tid >> 7;
  const int i = tid & 127;
  const bool active = (kind == 0) || (grp == 0);
  const bool colread = (kind == 0) && (grp == 1);

  f32x4 crow[32];
  if (active) {
    if (colread) {
#pragma unroll
      for (int jj = 0; jj < 32; jj++) {
        f32x4 v;
        v[0] = CL[(4 * jj + 0) * CPAD + i];
        v[1] = CL[(4 * jj + 1) * CPAD + i];
        v[2] = CL[(4 * jj + 2) * CPAD + i];
        v[3] = CL[(4 * jj + 3) * CPAD + i];
        crow[jj] = v;
      }
    } else {
#pragma unroll
      for (int jj = 0; jj < 32; jj++)
        crow[jj] = *(const f32x4*)&CL[i * CPAD + 4 * jj];
    }
  }

  float eps = 1.0f;
  for (int it = 0; it < 9; it++) {
    if (it == 8) eps = 2.5e-5f;             // BLUR^P
    const float inv_eps = 1.0f / eps;
    const float damp = 1.0f / (1.0f + eps / rho);
    const float ebl = eps * AL;

    float newp = 0.f;
    if (active) {
      const f32x4* h = (kind == 0 && grp == 0) ? h4b : h4a;
      f32x4 m4 = (f32x4){-3.0e38f, -3.0e38f, -3.0e38f, -3.0e38f};
#pragma unroll
      for (int jj = 0; jj < 32; jj++) {
        const f32x4 u = h[jj] - crow[jj];
        m4[0] = fmaxf(m4[0], u[0]); m4[1] = fmaxf(m4[1], u[1]);
        m4[2] = fmaxf(m4[2], u[2]); m4[3] = fmaxf(m4[3], u[3]);
      }
      const float m = fmaxf(fmaxf(m4[0], m4[1]), fmaxf(m4[2], m4[3]));
      const float k = inv_eps * LOG2E;
      f32x4 s4 = (f32x4){0.f, 0.f, 0.f, 0.f};
#pragma unroll
      for (int jj = 0; jj < 32; jj++) {
        const f32x4 u = h[jj] - crow[jj];
        s4[0] += __builtin_exp2f((u[0] - m) * k);
        s4[1] += __builtin_exp2f((u[1] - m) * k);
        s4[2] += __builtin_exp2f((u[2] - m) * k);
        s4[3] += __builtin_exp2f((u[3] - m) * k);
      }
      const float Ssum = (s4[0] + s4[1]) + (s4[2] + s4[3]);   // >= 1
      const float sm = -(m + ebl + eps * (LN2 * __log2f(Ssum)));
      if (kind == 0) newp = damp * sm;
      else           newp = 0.5f * (((const float*)h4a)[i] + damp * sm);
    }
    __syncthreads();
    if (active) {
      if (grp == 0) ((float*)h4a)[i] = newp;
      else          ((float*)h4b)[i] = newp;
    }
    __syncthreads();
    eps *= 0.25f;                           // SCALING^P
  }

  float v = 0.f;
  if (kind == 0) {
    v = (grp == 0) ? -__expf(-((const float*)h4a)[i] / rho)
                   : -__expf(-((const float*)h4b)[i] / rho);
  } else if (grp == 0) {
    v = __expf(-((const float*)h4a)[i] / rho);
  }
  red[tid] = v;
  __syncthreads();
  for (int st = 128; st > 0; st >>= 1) {
    if (tid < st) red[tid] += red[tid + st];
    __syncthreads();
  }
  if (tid == 0) kdpart[pair * 3 + kind] = red[0];
}

// ---------------------------------------------------------------------------
// Kernel 4: one-hot gather. ONE WAVE per (b,s) — ballot+shfl, no LDS/barrier.
// ---------------------------------------------------------------------------
__global__ __launch_bounds__(256) void ps_kernel(
    const float* __restrict__ lc, const float* __restrict__ lt, const float* __restrict__ le,
    const float* __restrict__ batch,
    float* __restrict__ pc, float* __restrict__ pt, float* __restrict__ pe,
    float* __restrict__ aarr) {
  const int w = blockIdx.x * 4 + (threadIdx.x >> 6);   // wave id = b*S_DIM+s
  if (w >= NB * S_DIM) return;
  const int lane = threadIdx.x & 63;
  const int b = w / S_DIM, s = w - b * S_DIM;
  const float* brow = batch + ((size_t)b * T_DIM + (s + 1)) * (2 * Q_DIM);

  int qv = 0; float dsv = 0.f; bool found = false;
#pragma unroll
  for (int c = 0; c < 4; c++) {
    const int base = c * 256 + lane * 4;             // coalesced f32x4
    const f32x4 d0 = *(const f32x4*)(brow + base);
    const f32x4 d1 = *(const f32x4*)(brow + Q_DIM + base);
#pragma unroll
    for (int j = 0; j < 4; j++)
      if (d0[j] + d1[j] > 0.5f) { qv = base + j; dsv = d0[j] - d1[j]; found = true; }
  }
  const unsigned long long m = __ballot(found);
  const int src = (m != 0ull) ? (__ffsll((unsigned long long)m) - 1) : 0;
  qv = __shfl(qv, src, 64);
  dsv = __shfl(dsv, src, 64);
  if (lane == 0) {
    const size_t off = ((size_t)b * T_DIM + s) * Q_DIM + qv;
    pc[w] = 2.0f * lc[off];   // 1/TEMP
    pt[w] = 2.0f * lt[off];
    pe[w] = 2.0f * le[off];
    aarr[w] = (m != 0ull && dsv > 0.0f) ? 1.0f : 0.0f;
  }
}

// ---------------------------------------------------------------------------
// Kernel 5: embed loss: sum of squared diffs. 1600 blocks = 1 tile/thread.
// ---------------------------------------------------------------------------
__global__ __launch_bounds__(256) void embed_kernel(
    const f32x4* __restrict__ hs, const f32x4* __restrict__ ht,
    const f32x4* __restrict__ ds, const f32x4* __restrict__ dt,
    float* __restrict__ acc) {
  const int N4 = NB * T_DIM * H_DIM / 4;   // 409600
  float sum = 0.f;
  for (int idx = blockIdx.x * 256 + threadIdx.x; idx < N4; idx += gridDim.x * 256) {
    f32x4 a = hs[idx] - ht[idx];
    f32x4 b = ds[idx] - dt[idx];
    sum += a[0]*a[0] + a[1]*a[1] + a[2]*a[2] + a[3]*a[3]
         + b[0]*b[0] + b[1]*b[1] + b[2]*b[2] + b[3]*b[3];
  }
  for (int off = 32; off > 0; off >>= 1) sum += __shfl_down(sum, off, 64);
  __shared__ float wsum[4];
  const int lane = threadIdx.x & 63, wv = threadIdx.x >> 6;
  if (lane == 0) wsum[wv] = sum;
  __syncthreads();
  if (threadIdx.x == 0) atomicAdd(acc, wsum[0] + wsum[1] + wsum[2] + wsum[3]);
}

// ---------------------------------------------------------------------------
// Kernel 6: masked CE + final combine. 1 block, 128 threads. LDS-staged.
// ---------------------------------------------------------------------------
__global__ __launch_bounds__(128) void ce_final_kernel(
    const float* __restrict__ pc, const float* __restrict__ pt, const float* __restrict__ pe,
    const float* __restrict__ aarr, const float* __restrict__ kdpart,
    const float* __restrict__ emb, float* __restrict__ out) {
  __shared__ float sx[4][NB][S_DIM];   // 0:pt 1:pc 2:pe 3:a — 100352 B
  const int tid = threadIdx.x;
  for (int idx = tid; idx < NB * S_DIM; idx += 128) {
    const int b = idx / S_DIM, s = idx - b * S_DIM;
    sx[0][b][s] = pt[idx];
    sx[1][b][s] = pc[idx];
    sx[2][b][s] = pe[idx];
    sx[3][b][s] = aarr[idx];
  }
  __syncthreads();

  const int b = tid;
  int last = -1;
  for (int s = 0; s < S_DIM; s++)
    if (sx[1][b][s] > 0.0f) last = s;
  const int L = (last >= 0) ? (last + 1) : S_DIM;

  float loss = 0.f;
#pragma unroll
  for (int k = 0; k < 3; k++) {
    float m = -3.0e38f;
    for (int s = 0; s < L; s++) m = fmaxf(m, sx[k][b][s]);
    float sum = 0.f;
    for (int s = 0; s < L; s++) sum += __expf(sx[k][b][s] - m);
    const float lse = m + __logf(sum);
    float l = 0.f;
    for (int s = 0; s < L; s++) l += sx[3][b][s] * (sx[k][b][s] - lse);
    loss -= l;
  }

  __shared__ float red[128];
  red[b] = loss;
  __syncthreads();
  for (int st = 64; st > 0; st >>= 1) {
    if (b < st) red[b] += red[b + st];
    __syncthreads();
  }
  if (b == 0) {
    float kd = 0.f;
    for (int k = 0; k < 9; k++) kd += kdpart[k];
    // w * a_w = (rho + eps_final/2) / 128 ; DIST_W = 0.01
    out[0] = red[0] + 0.01f * (250000.0000125f / 128.0f) * kd + 0.5f * emb[0];
  }
}

// ---------------------------------------------------------------------------
extern "C" void kernel_launch(void* const* d_in, const int* in_sizes, int n_in,
                              void* d_out, int out_size, void* d_ws, size_t ws_size,
                              hipStream_t stream) {
  const float* lc    = (const float*)d_in[0];
  const float* lt    = (const float*)d_in[1];
  const float* le    = (const float*)d_in[2];
  const float* ltc   = (const float*)d_in[3];
  const float* ltt   = (const float*)d_in[4];
  const float* lte   = (const float*)d_in[5];
  const float* ohs   = (const float*)d_in[6];
  const float* oht   = (const float*)d_in[7];
  const float* ods   = (const float*)d_in[8];
  const float* odt   = (const float*)d_in[9];
  const float* batch = (const float*)d_in[10];

  const size_t tilesBytes = (size_t)6 * NTILE * TSTRU * 4;          // 79,872,000
  const size_t partBytes  = (size_t)9 * KCHUNKS * GRAM_N * 2;       // 23,592,960
  const size_t tailBytes  = ((size_t)9 * GRAM_N + 4 * NB * S_DIM + 16) * 4;
  const bool useTiles = (ws_size >= tilesBytes + partBytes + tailBytes);

  unsigned int* tiles = (unsigned int*)d_ws;
  unsigned short* part = useTiles
      ? (unsigned short*)((char*)d_ws + tilesBytes)
      : (unsigned short*)d_ws;
  float* gram = (float*)((char*)part + partBytes);
  float* pcb  = gram + 9 * GRAM_N;                     // 128*49 each
  float* ptb  = pcb + NB * S_DIM;
  float* peb  = ptb + NB * S_DIM;
  float* ab   = peb + NB * S_DIM;
  float* kdp  = ab + NB * S_DIM;                       // 9
  float* emb  = kdp + 9;                               // 1

  hipMemsetAsync(emb, 0, sizeof(float), stream);

  embed_kernel<<<1600, 256, 0, stream>>>(
      (const f32x4*)ohs, (const f32x4*)oht, (const f32x4*)ods, (const f32x4*)odt, emb);

  ps_kernel<<<(NB * S_DIM + 3) / 4, 256, 0, stream>>>(lc, lt, le, batch, pcb, ptb, peb, ab);

  if (useTiles) {
    convert_kernel<<<6 * NB, 256, 0, stream>>>(lc, lt, le, ltc, ltt, lte, tiles);
    gram_tiles_kernel<<<dim3(KCHUNKS, 3), 1024, 0, stream>>>(tiles, part);
  } else {
    gram_fused_legacy<<<dim3(KCHUNKS, 3), 1024, 0, stream>>>(lc, lt, le, ltc, ltt, lte, part);
  }

  gram_reduce_kernel<<<(9 * GRAM_N) / 256, 256, 0, stream>>>(part, gram);

  sinkhorn_part_kernel<<<dim3(3, 3), 256, 0, stream>>>(gram, kdp);

  ce_final_kernel<<<1, 128, 0, stream>>>(pcb, ptb, peb, ab, kdp, emb, (float*)d_out);
}

// Round 8
// 323.363 us; speedup vs baseline: 1.3000x; 1.3000x over previous
//
#include <hip/hip_runtime.h>

#define NB 128
#define T_DIM 50
#define Q_DIM 1024
#define H_DIM 256
#define S_DIM 49                 // MAX_STEP - 1
#define K_DIM 51200              // T*Q
#define KCHUNKS 80
#define KC 640                   // K per chunk
#define BK 64                    // K per LDS stage
#define NSTAGE 10                // KC/BK
#define GRAM_N (NB * NB)         // 16384
#define LROWU 36                 // uints per padded LDS row (64 f16 + 8 pad)
#define CPAD 132                 // padded f32 row for sinkhorn cost matrix
#define PS_BLOCKS ((NB * S_DIM + 3) / 4)   // 1568
#define EMB_BLOCKS 1600

typedef __attribute__((ext_vector_type(4))) float f32x4;
typedef __attribute__((ext_vector_type(8))) _Float16 half8v;
typedef __attribute__((ext_vector_type(4))) unsigned int uint4v;
typedef __attribute__((ext_vector_type(2))) unsigned int uint2v;
using pk2_t = decltype(__builtin_amdgcn_cvt_pkrtz(0.0f, 0.0f));

union PKU { pk2_t p; unsigned int u; };
union U4H8 { uint4v u; half8v h; };

__device__ inline unsigned short f2bf_rn(float x) {   // round-nearest-even bf16
  union { float f; unsigned int u; } v; v.f = x;
  unsigned int r = v.u + 0x7FFFu + ((v.u >> 16) & 1u);
  return (unsigned short)(r >> 16);
}
__device__ inline float bf2f(unsigned short b) {
  union { float f; unsigned int u; } v; v.u = ((unsigned int)b) << 16;
  return v.f;
}

// ---------------------------------------------------------------------------
// gram helpers (round-4 verified legacy path, 66.6us)
// ---------------------------------------------------------------------------
__device__ __forceinline__ void issue_loads(
    const float* __restrict__ S, const float* __restrict__ Tm,
    size_t ro0, size_t ro1, int kpos, int kq,
    f32x4& p0, f32x4& p1, f32x4& p2, f32x4& p3) {
  const float* pS = S + kpos + kq * 4;
  const float* pT = Tm + kpos + kq * 4;
  p0 = *(const f32x4*)(pS + ro0);
  p1 = *(const f32x4*)(pS + ro1);
  p2 = *(const f32x4*)(pT + ro0);
  p3 = *(const f32x4*)(pT + ro1);
}

__device__ __forceinline__ void cvt_write(
    unsigned int* __restrict__ panA, unsigned int* __restrict__ panB,
    int r0, int kq,
    const f32x4& p0, const f32x4& p1, const f32x4& p2, const f32x4& p3) {
  PKU a, b; uint2v w;
  a.p = __builtin_amdgcn_cvt_pkrtz(p0[0], p0[1]);
  b.p = __builtin_amdgcn_cvt_pkrtz(p0[2], p0[3]);
  w.x = a.u; w.y = b.u;
  *(uint2v*)&panA[r0 * LROWU + kq * 2] = w;
  a.p = __builtin_amdgcn_cvt_pkrtz(p1[0], p1[1]);
  b.p = __builtin_amdgcn_cvt_pkrtz(p1[2], p1[3]);
  w.x = a.u; w.y = b.u;
  *(uint2v*)&panA[(r0 + 64) * LROWU + kq * 2] = w;
  a.p = __builtin_amdgcn_cvt_pkrtz(p2[0], p2[1]);
  b.p = __builtin_amdgcn_cvt_pkrtz(p2[2], p2[3]);
  w.x = a.u; w.y = b.u;
  *(uint2v*)&panB[r0 * LROWU + kq * 2] = w;
  a.p = __builtin_amdgcn_cvt_pkrtz(p3[0], p3[1]);
  b.p = __builtin_amdgcn_cvt_pkrtz(p3[2], p3[3]);
  w.x = a.u; w.y = b.u;
  *(uint2v*)&panB[(r0 + 64) * LROWU + kq * 2] = w;
}

__device__ __forceinline__ void compute_stage(
    const unsigned int* __restrict__ panA, const unsigned int* __restrict__ panB,
    int wrow, int wcol, int l15, int quad,
    f32x4 (&aXY)[2][2], f32x4 (&aXX)[2][2], f32x4 (&aYY)[2][2]) {
#pragma unroll
  for (int ks = 0; ks < 2; ks++) {
    const int kc = ks * 16 + quad * 4;
    half8v as_[2], bs_[2], at_[2], bt_[2];
#pragma unroll
    for (int t = 0; t < 2; t++) {
      U4H8 u;
      u.u = *(const uint4v*)&panA[(wrow * 32 + t * 16 + l15) * LROWU + kc]; as_[t] = u.h;
      u.u = *(const uint4v*)&panA[(wcol * 32 + t * 16 + l15) * LROWU + kc]; bs_[t] = u.h;
      u.u = *(const uint4v*)&panB[(wrow * 32 + t * 16 + l15) * LROWU + kc]; at_[t] = u.h;
      u.u = *(const uint4v*)&panB[(wcol * 32 + t * 16 + l15) * LROWU + kc]; bt_[t] = u.h;
    }
#pragma unroll
    for (int ti = 0; ti < 2; ti++)
#pragma unroll
      for (int tj = 0; tj < 2; tj++) {
        aXY[ti][tj] = __builtin_amdgcn_mfma_f32_16x16x32_f16(as_[ti], bt_[tj], aXY[ti][tj], 0, 0, 0);
        aXX[ti][tj] = __builtin_amdgcn_mfma_f32_16x16x32_f16(as_[ti], bs_[tj], aXX[ti][tj], 0, 0, 0);
        aYY[ti][tj] = __builtin_amdgcn_mfma_f32_16x16x32_f16(at_[ti], bt_[tj], aYY[ti][tj], 0, 0, 0);
      }
  }
}

// ---------------------------------------------------------------------------
// Kernel 1: FUSED per-pair grams (round-4 verified legacy, 66.6us).
// Round-8: reverted from the two-pass tiles experiment — convert cost 119us
// (scattered writes at 16640B stride went to HBM at 1.9TB/s) while
// gram-from-tiles hit ~25us; two-pass floor (237MB traffic) ~= one-pass 67us.
// ---------------------------------------------------------------------------
__global__ __launch_bounds__(1024) void gram_fused_kernel(
    const float* __restrict__ s0, const float* __restrict__ s1, const float* __restrict__ s2,
    const float* __restrict__ t0, const float* __restrict__ t1, const float* __restrict__ t2,
    unsigned short* __restrict__ part) {
  __shared__ unsigned int pan[2][2][NB * LROWU];   // [buf][A/B], 73728 B

  const int chunk = blockIdx.x;
  const int pair = blockIdx.y;
  const float* S  = (pair == 0) ? s0 : ((pair == 1) ? s1 : s2);
  const float* Tm = (pair == 0) ? t0 : ((pair == 1) ? t1 : t2);

  const int tid = threadIdx.x;
  const int wave = tid >> 6, lane = tid & 63;
  const int wrow = wave >> 2, wcol = wave & 3;
  const int l15 = lane & 15, quad = lane >> 4;

  f32x4 aXY[2][2], aXX[2][2], aYY[2][2];
#pragma unroll
  for (int i = 0; i < 2; i++)
#pragma unroll
    for (int j = 0; j < 2; j++) {
      aXY[i][j] = (f32x4){0.f, 0.f, 0.f, 0.f};
      aXX[i][j] = (f32x4){0.f, 0.f, 0.f, 0.f};
      aYY[i][j] = (f32x4){0.f, 0.f, 0.f, 0.f};
    }

  const int r0 = tid >> 4;              // 0..63 (i=0); i=1 -> r0+64
  const int kq = tid & 15;
  const size_t ro0 = (size_t)r0 * K_DIM;
  const size_t ro1 = (size_t)(r0 + 64) * K_DIM;
  const int kbase = chunk * KC;

  f32x4 A0, A1, A2, A3;   // even-stage prefetch set
  f32x4 B0, B1, B2, B3;   // odd-stage prefetch set

  issue_loads(S, Tm, ro0, ro1, kbase, kq, A0, A1, A2, A3);
  issue_loads(S, Tm, ro0, ro1, kbase + BK, kq, B0, B1, B2, B3);
  cvt_write(&pan[0][0][0], &pan[0][1][0], r0, kq, A0, A1, A2, A3);
  __syncthreads();

  for (int s2 = 0; s2 < NSTAGE; s2 += 2) {
    if (s2 + 2 < NSTAGE)
      issue_loads(S, Tm, ro0, ro1, kbase + (s2 + 2) * BK, kq, A0, A1, A2, A3);
    compute_stage(&pan[0][0][0], &pan[0][1][0], wrow, wcol, l15, quad, aXY, aXX, aYY);
    cvt_write(&pan[1][0][0], &pan[1][1][0], r0, kq, B0, B1, B2, B3);
    __syncthreads();

    if (s2 + 3 < NSTAGE)
      issue_loads(S, Tm, ro0, ro1, kbase + (s2 + 3) * BK, kq, B0, B1, B2, B3);
    compute_stage(&pan[1][0][0], &pan[1][1][0], wrow, wcol, l15, quad, aXY, aXX, aYY);
    if (s2 + 2 < NSTAGE) {
      cvt_write(&pan[0][0][0], &pan[0][1][0], r0, kq, A0, A1, A2, A3);
      __syncthreads();
    }
  }

#pragma unroll
  for (int kind = 0; kind < 3; kind++) {
    unsigned short* out = part + ((size_t)(pair * 3 + kind) * KCHUNKS + chunk) * GRAM_N;
#pragma unroll
    for (int ti = 0; ti < 2; ti++)
#pragma unroll
      for (int tj = 0; tj < 2; tj++) {
        const f32x4 v = (kind == 0) ? aXY[ti][tj] : ((kind == 1) ? aXX[ti][tj] : aYY[ti][tj]);
        const int col = wcol * 32 + tj * 16 + l15;
#pragma unroll
        for (int r = 0; r < 4; r++) {
          const int row = wrow * 32 + ti * 16 + quad * 4 + r;
          out[(size_t)row * NB + col] = f2bf_rn(v[r]);
        }
      }
  }
}

// ---------------------------------------------------------------------------
// Kernel 2: reduce bf16 K-chunk partials -> gram[9][128][128] (f32)
// ---------------------------------------------------------------------------
__global__ __launch_bounds__(256) void gram_reduce_kernel(
    const unsigned short* __restrict__ part, float* __restrict__ gram) {
  const int idx = blockIdx.x * 256 + threadIdx.x;   // < 9*16384
  const int g = idx >> 14;
  const int cell = idx & (GRAM_N - 1);
  const unsigned short* p = part + (size_t)g * KCHUNKS * GRAM_N + cell;
  float s = 0.f;
#pragma unroll
  for (int c = 0; c < KCHUNKS; c++) s += bf2f(p[(size_t)c * GRAM_N]);
  gram[idx] = s;
}

// ---------------------------------------------------------------------------
// Kernel 3: Sinkhorn, per (pair, kind) chain. (unchanged — verified 6x)
// ---------------------------------------------------------------------------
__global__ __launch_bounds__(256, 1) void sinkhorn_part_kernel(
    const float* __restrict__ gram, float* __restrict__ kdpart) {
  const int pair = blockIdx.x, kind = blockIdx.y;
  const float* Gxy = gram + (size_t)(3 * pair + 0) * GRAM_N;
  const float* Gxx = gram + (size_t)(3 * pair + 1) * GRAM_N;
  const float* Gyy = gram + (size_t)(3 * pair + 2) * GRAM_N;

  __shared__ float CL[NB * CPAD];     // 67584 B, f32 cost matrix
  __shared__ f32x4 h4a[NB / 4];       // pot0 (f-side)
  __shared__ f32x4 h4b[NB / 4];       // pot1 (g-side, kind0 only)
  __shared__ float nx[NB], ny[NB];
  __shared__ float red[256];

  const int tid = threadIdx.x;
  if (tid < NB) {
    nx[tid] = Gxx[tid * (NB + 1)];
    ny[tid] = Gyy[tid * (NB + 1)];
    ((float*)h4a)[tid] = 0.f;
    ((float*)h4b)[tid] = 0.f;
  }
  __syncthreads();

  const float* G  = (kind == 0) ? Gxy : ((kind == 1) ? Gxx : Gyy);
  const float* rn = (kind == 2) ? ny : nx;
  const float* cn = (kind == 1) ? nx : ny;
  for (int idx = tid; idx < GRAM_N; idx += 256) {
    const int i = idx >> 7, j = idx & 127;
    CL[i * CPAD + j] = 2.0f * fmaxf(rn[i] + cn[j] - 2.0f * G[idx], 0.0f);
  }
  __syncthreads();

  const float rho = 250000.0f;
  const float AL = -4.852030263919617f;     // -log(128)
  const float LOG2E = 1.4426950408889634f;
  const float LN2 = 0.6931471805599453f;
  const int grp = tid >> 7;
  const int i = tid & 127;
  const bool active = (kind == 0) || (grp == 0);
  const bool colread = (kind == 0) && (grp == 1);

  f32x4 crow[32];
  if (active) {
    if (colread) {
#pragma unroll
      for (int jj = 0; jj < 32; jj++) {
        f32x4 v;
        v[0] = CL[(4 * jj + 0) * CPAD + i];
        v[1] = CL[(4 * jj + 1) * CPAD + i];
        v[2] = CL[(4 * jj + 2) * CPAD + i];
        v[3] = CL[(4 * jj + 3) * CPAD + i];
        crow[jj] = v;
      }
    } else {
#pragma unroll
      for (int jj = 0; jj < 32; jj++)
        crow[jj] = *(const f32x4*)&CL[i * CPAD + 4 * jj];
    }
  }

  float eps = 1.0f;
  for (int it = 0; it < 9; it++) {
    if (it == 8) eps = 2.5e-5f;             // BLUR^P
    const float inv_eps = 1.0f / eps;
    const float damp = 1.0f / (1.0f + eps / rho);
    const float ebl = eps * AL;

    float newp = 0.f;
    if (active) {
      const f32x4* h = (kind == 0 && grp == 0) ? h4b : h4a;
      f32x4 m4 = (f32x4){-3.0e38f, -3.0e38f, -3.0e38f, -3.0e38f};
#pragma unroll
      for (int jj = 0; jj < 32; jj++) {
        const f32x4 u = h[jj] - crow[jj];
        m4[0] = fmaxf(m4[0], u[0]); m4[1] = fmaxf(m4[1], u[1]);
        m4[2] = fmaxf(m4[2], u[2]); m4[3] = fmaxf(m4[3], u[3]);
      }
      const float m = fmaxf(fmaxf(m4[0], m4[1]), fmaxf(m4[2], m4[3]));
      const float k = inv_eps * LOG2E;
      f32x4 s4 = (f32x4){0.f, 0.f, 0.f, 0.f};
#pragma unroll
      for (int jj = 0; jj < 32; jj++) {
        const f32x4 u = h[jj] - crow[jj];
        s4[0] += __builtin_exp2f((u[0] - m) * k);
        s4[1] += __builtin_exp2f((u[1] - m) * k);
        s4[2] += __builtin_exp2f((u[2] - m) * k);
        s4[3] += __builtin_exp2f((u[3] - m) * k);
      }
      const float Ssum = (s4[0] + s4[1]) + (s4[2] + s4[3]);   // >= 1
      const float sm = -(m + ebl + eps * (LN2 * __log2f(Ssum)));
      if (kind == 0) newp = damp * sm;
      else           newp = 0.5f * (((const float*)h4a)[i] + damp * sm);
    }
    __syncthreads();
    if (active) {
      if (grp == 0) ((float*)h4a)[i] = newp;
      else          ((float*)h4b)[i] = newp;
    }
    __syncthreads();
    eps *= 0.25f;                           // SCALING^P
  }

  float v = 0.f;
  if (kind == 0) {
    v = (grp == 0) ? -__expf(-((const float*)h4a)[i] / rho)
                   : -__expf(-((const float*)h4b)[i] / rho);
  } else if (grp == 0) {
    v = __expf(-((const float*)h4a)[i] / rho);
  }
  red[tid] = v;
  __syncthreads();
  for (int st = 128; st > 0; st >>= 1) {
    if (tid < st) red[tid] += red[tid + st];
    __syncthreads();
  }
  if (tid == 0) kdpart[pair * 3 + kind] = red[0];
}

// ---------------------------------------------------------------------------
// Kernel 4 (FUSED): ps gather + embed partial sums.
// Round-8: dispatch-count reduction — tail has been a constant ~276us across
// rounds 3/4/5/7 while per-kernel pipe arithmetic sums to ~45us; testing the
// ~10us/dispatch launch-overhead hypothesis by cutting our dispatches 8->5.
// Blocks [0, PS_BLOCKS): ps (wave per (b,s), ballot+shfl).
// Blocks [PS_BLOCKS, PS_BLOCKS+EMB_BLOCKS): embed -> embPart[eb] (no atomic,
// no memset; ce_final tree-sums the 1600 partials).
// Branch is block-uniform -> __syncthreads in embed branch is safe.
// ---------------------------------------------------------------------------
__global__ __launch_bounds__(256) void ps_embed_kernel(
    const float* __restrict__ lc, const float* __restrict__ lt, const float* __restrict__ le,
    const float* __restrict__ batch,
    const f32x4* __restrict__ hs, const f32x4* __restrict__ ht,
    const f32x4* __restrict__ ds, const f32x4* __restrict__ dt,
    float* __restrict__ pc, float* __restrict__ pt, float* __restrict__ pe,
    float* __restrict__ aarr, float* __restrict__ embPart) {
  const int bid = blockIdx.x;
  if (bid < PS_BLOCKS) {
    const int w = bid * 4 + (threadIdx.x >> 6);     // wave id = b*S_DIM+s
    if (w >= NB * S_DIM) return;
    const int lane = threadIdx.x & 63;
    const int b = w / S_DIM, s = w - b * S_DIM;
    const float* brow = batch + ((size_t)b * T_DIM + (s + 1)) * (2 * Q_DIM);

    int qv = 0; float dsv = 0.f; bool found = false;
#pragma unroll
    for (int c = 0; c < 4; c++) {
      const int base = c * 256 + lane * 4;          // coalesced f32x4
      const f32x4 d0 = *(const f32x4*)(brow + base);
      const f32x4 d1 = *(const f32x4*)(brow + Q_DIM + base);
#pragma unroll
      for (int j = 0; j < 4; j++)
        if (d0[j] + d1[j] > 0.5f) { qv = base + j; dsv = d0[j] - d1[j]; found = true; }
    }
    const unsigned long long m = __ballot(found);
    const int src = (m != 0ull) ? (__ffsll((unsigned long long)m) - 1) : 0;
    qv = __shfl(qv, src, 64);
    dsv = __shfl(dsv, src, 64);
    if (lane == 0) {
      const size_t off = ((size_t)b * T_DIM + s) * Q_DIM + qv;
      pc[w] = 2.0f * lc[off];   // 1/TEMP
      pt[w] = 2.0f * lt[off];
      pe[w] = 2.0f * le[off];
      aarr[w] = (m != 0ull && dsv > 0.0f) ? 1.0f : 0.0f;
    }
  } else {
    const int eb = bid - PS_BLOCKS;
    const int N4 = NB * T_DIM * H_DIM / 4;   // 409600
    float sum = 0.f;
    for (int idx = eb * 256 + threadIdx.x; idx < N4; idx += EMB_BLOCKS * 256) {
      f32x4 a = hs[idx] - ht[idx];
      f32x4 b = ds[idx] - dt[idx];
      sum += a[0]*a[0] + a[1]*a[1] + a[2]*a[2] + a[3]*a[3]
           + b[0]*b[0] + b[1]*b[1] + b[2]*b[2] + b[3]*b[3];
    }
    for (int off = 32; off > 0; off >>= 1) sum += __shfl_down(sum, off, 64);
    __shared__ float wsum[4];
    const int lane = threadIdx.x & 63, wv = threadIdx.x >> 6;
    if (lane == 0) wsum[wv] = sum;
    __syncthreads();
    if (threadIdx.x == 0) embPart[eb] = wsum[0] + wsum[1] + wsum[2] + wsum[3];
  }
}

// ---------------------------------------------------------------------------
// Kernel 5: masked CE + embed-partial sum + final combine. 1 block, 128 thr.
// ---------------------------------------------------------------------------
__global__ __launch_bounds__(128) void ce_final_kernel(
    const float* __restrict__ pc, const float* __restrict__ pt, const float* __restrict__ pe,
    const float* __restrict__ aarr, const float* __restrict__ kdpart,
    const float* __restrict__ embPart, float* __restrict__ out) {
  __shared__ float sx[4][NB][S_DIM];   // 0:pt 1:pc 2:pe 3:a — 100352 B
  const int tid = threadIdx.x;
  for (int idx = tid; idx < NB * S_DIM; idx += 128) {
    const int b = idx / S_DIM, s = idx - b * S_DIM;
    sx[0][b][s] = pt[idx];
    sx[1][b][s] = pc[idx];
    sx[2][b][s] = pe[idx];
    sx[3][b][s] = aarr[idx];
  }
  float esum = 0.f;
  for (int i = tid; i < EMB_BLOCKS; i += 128) esum += embPart[i];
  __syncthreads();

  const int b = tid;
  int last = -1;
  for (int s = 0; s < S_DIM; s++)
    if (sx[1][b][s] > 0.0f) last = s;
  const int L = (last >= 0) ? (last + 1) : S_DIM;

  float loss = 0.f;
#pragma unroll
  for (int k = 0; k < 3; k++) {
    float m = -3.0e38f;
    for (int s = 0; s < L; s++) m = fmaxf(m, sx[k][b][s]);
    float sum = 0.f;
    for (int s = 0; s < L; s++) sum += __expf(sx[k][b][s] - m);
    const float lse = m + __logf(sum);
    float l = 0.f;
    for (int s = 0; s < L; s++) l += sx[3][b][s] * (sx[k][b][s] - lse);
    loss -= l;
  }

  __shared__ float red[128];
  __shared__ float rede[128];
  red[b] = loss;
  rede[b] = esum;
  __syncthreads();
  for (int st = 64; st > 0; st >>= 1) {
    if (b < st) { red[b] += red[b + st]; rede[b] += rede[b + st]; }
    __syncthreads();
  }
  if (b == 0) {
    float kd = 0.f;
    for (int k = 0; k < 9; k++) kd += kdpart[k];
    // w * a_w = (rho + eps_final/2) / 128 ; DIST_W = 0.01
    out[0] = red[0] + 0.01f * (250000.0000125f / 128.0f) * kd + 0.5f * rede[0];
  }
}

// ---------------------------------------------------------------------------
extern "C" void kernel_launch(void* const* d_in, const int* in_sizes, int n_in,
                              void* d_out, int out_size, void* d_ws, size_t ws_size,
                              hipStream_t stream) {
  const float* lc    = (const float*)d_in[0];
  const float* lt    = (const float*)d_in[1];
  const float* le    = (const float*)d_in[2];
  const float* ltc   = (const float*)d_in[3];
  const float* ltt   = (const float*)d_in[4];
  const float* lte   = (const float*)d_in[5];
  const float* ohs   = (const float*)d_in[6];
  const float* oht   = (const float*)d_in[7];
  const float* ods   = (const float*)d_in[8];
  const float* odt   = (const float*)d_in[9];
  const float* batch = (const float*)d_in[10];

  unsigned short* part = (unsigned short*)d_ws;        // 9*80*16384*2B = 23.6 MB
  float* gram = (float*)(part + (size_t)9 * KCHUNKS * GRAM_N);  // 9*16384 f32
  float* pcb  = gram + 9 * GRAM_N;                     // 128*49 each
  float* ptb  = pcb + NB * S_DIM;
  float* peb  = ptb + NB * S_DIM;
  float* ab   = peb + NB * S_DIM;
  float* kdp  = ab + NB * S_DIM;                       // 9
  float* embp = kdp + 9;                               // 1600

  // Dispatch 1: fused ps + embed (no memset needed — embed uses partials)
  ps_embed_kernel<<<PS_BLOCKS + EMB_BLOCKS, 256, 0, stream>>>(
      lc, lt, le, batch,
      (const f32x4*)ohs, (const f32x4*)oht, (const f32x4*)ods, (const f32x4*)odt,
      pcb, ptb, peb, ab, embp);

  // Dispatch 2: gram (legacy round-4, verified 66.6us)
  gram_fused_kernel<<<dim3(KCHUNKS, 3), 1024, 0, stream>>>(lc, lt, le, ltc, ltt, lte, part);

  // Dispatch 3: partial reduce
  gram_reduce_kernel<<<(9 * GRAM_N) / 256, 256, 0, stream>>>(part, gram);

  // Dispatch 4: sinkhorn chains
  sinkhorn_part_kernel<<<dim3(3, 3), 256, 0, stream>>>(gram, kdp);

  // Dispatch 5: CE + embed-sum + combine
  ce_final_kernel<<<1, 128, 0, stream>>>(pcb, ptb, peb, ab, kdp, embp, (float*)d_out);
}

// Round 9
// 319.682 us; speedup vs baseline: 1.3150x; 1.0115x over previous
//
#include <hip/hip_runtime.h>

#define NB 128
#define T_DIM 50
#define Q_DIM 1024
#define H_DIM 256
#define S_DIM 49                 // MAX_STEP - 1
#define K_DIM 51200              // T*Q
#define KCHUNKS 80
#define KC 640                   // K per chunk
#define BK 64                    // K per LDS stage
#define NSTAGE 10                // KC/BK
#define GRAM_N (NB * NB)         // 16384
#define LROWU 36                 // uints per padded LDS row (64 f16 + 8 pad)
#define CPAD 132                 // padded f32 row for sinkhorn cost matrix

// mega-kernel block ranges (dispatch 1)
#define GRAM_BLOCKS 240                      // 80 chunks x 3 pairs, 1024 thr
#define PS_BLOCKS 392                        // 6272 waves / 16
#define EMB_BLOCKS 400                       // 409600 f32x4 / 1024
#define PS_BASE GRAM_BLOCKS                  // 240
#define EMB_BASE (GRAM_BLOCKS + PS_BLOCKS)   // 632
#define TOTAL_BLOCKS (EMB_BASE + EMB_BLOCKS) // 1032

typedef __attribute__((ext_vector_type(4))) float f32x4;
typedef __attribute__((ext_vector_type(8))) _Float16 half8v;
typedef __attribute__((ext_vector_type(4))) unsigned int uint4v;
typedef __attribute__((ext_vector_type(2))) unsigned int uint2v;
using pk2_t = decltype(__builtin_amdgcn_cvt_pkrtz(0.0f, 0.0f));

union PKU { pk2_t p; unsigned int u; };
union U4H8 { uint4v u; half8v h; };

__device__ inline unsigned short f2bf_rn(float x) {   // round-nearest-even bf16
  union { float f; unsigned int u; } v; v.f = x;
  unsigned int r = v.u + 0x7FFFu + ((v.u >> 16) & 1u);
  return (unsigned short)(r >> 16);
}
__device__ inline float bf2f(unsigned short b) {
  union { float f; unsigned int u; } v; v.u = ((unsigned int)b) << 16;
  return v.f;
}

// ---------------------------------------------------------------------------
// gram helpers (round-4 verified, unchanged)
// ---------------------------------------------------------------------------
__device__ __forceinline__ void issue_loads(
    const float* __restrict__ S, const float* __restrict__ Tm,
    size_t ro0, size_t ro1, int kpos, int kq,
    f32x4& p0, f32x4& p1, f32x4& p2, f32x4& p3) {
  const float* pS = S + kpos + kq * 4;
  const float* pT = Tm + kpos + kq * 4;
  p0 = *(const f32x4*)(pS + ro0);
  p1 = *(const f32x4*)(pS + ro1);
  p2 = *(const f32x4*)(pT + ro0);
  p3 = *(const f32x4*)(pT + ro1);
}

__device__ __forceinline__ void cvt_write(
    unsigned int* __restrict__ panA, unsigned int* __restrict__ panB,
    int r0, int kq,
    const f32x4& p0, const f32x4& p1, const f32x4& p2, const f32x4& p3) {
  PKU a, b; uint2v w;
  a.p = __builtin_amdgcn_cvt_pkrtz(p0[0], p0[1]);
  b.p = __builtin_amdgcn_cvt_pkrtz(p0[2], p0[3]);
  w.x = a.u; w.y = b.u;
  *(uint2v*)&panA[r0 * LROWU + kq * 2] = w;
  a.p = __builtin_amdgcn_cvt_pkrtz(p1[0], p1[1]);
  b.p = __builtin_amdgcn_cvt_pkrtz(p1[2], p1[3]);
  w.x = a.u; w.y = b.u;
  *(uint2v*)&panA[(r0 + 64) * LROWU + kq * 2] = w;
  a.p = __builtin_amdgcn_cvt_pkrtz(p2[0], p2[1]);
  b.p = __builtin_amdgcn_cvt_pkrtz(p2[2], p2[3]);
  w.x = a.u; w.y = b.u;
  *(uint2v*)&panB[r0 * LROWU + kq * 2] = w;
  a.p = __builtin_amdgcn_cvt_pkrtz(p3[0], p3[1]);
  b.p = __builtin_amdgcn_cvt_pkrtz(p3[2], p3[3]);
  w.x = a.u; w.y = b.u;
  *(uint2v*)&panB[(r0 + 64) * LROWU + kq * 2] = w;
}

__device__ __forceinline__ void compute_stage(
    const unsigned int* __restrict__ panA, const unsigned int* __restrict__ panB,
    int wrow, int wcol, int l15, int quad,
    f32x4 (&aXY)[2][2], f32x4 (&aXX)[2][2], f32x4 (&aYY)[2][2]) {
#pragma unroll
  for (int ks = 0; ks < 2; ks++) {
    const int kc = ks * 16 + quad * 4;
    half8v as_[2], bs_[2], at_[2], bt_[2];
#pragma unroll
    for (int t = 0; t < 2; t++) {
      U4H8 u;
      u.u = *(const uint4v*)&panA[(wrow * 32 + t * 16 + l15) * LROWU + kc]; as_[t] = u.h;
      u.u = *(const uint4v*)&panA[(wcol * 32 + t * 16 + l15) * LROWU + kc]; bs_[t] = u.h;
      u.u = *(const uint4v*)&panB[(wrow * 32 + t * 16 + l15) * LROWU + kc]; at_[t] = u.h;
      u.u = *(const uint4v*)&panB[(wcol * 32 + t * 16 + l15) * LROWU + kc]; bt_[t] = u.h;
    }
#pragma unroll
    for (int ti = 0; ti < 2; ti++)
#pragma unroll
      for (int tj = 0; tj < 2; tj++) {
        aXY[ti][tj] = __builtin_amdgcn_mfma_f32_16x16x32_f16(as_[ti], bt_[tj], aXY[ti][tj], 0, 0, 0);
        aXX[ti][tj] = __builtin_amdgcn_mfma_f32_16x16x32_f16(as_[ti], bs_[tj], aXX[ti][tj], 0, 0, 0);
        aYY[ti][tj] = __builtin_amdgcn_mfma_f32_16x16x32_f16(at_[ti], bt_[tj], aYY[ti][tj], 0, 0, 0);
      }
  }
}

// ---------------------------------------------------------------------------
// Dispatch 1 (MEGA): gram + ps + embed, fused by disjoint block ranges.
// Round-9: dispatch-overhead model (fit r0..r8): dur ~= 167 fixed +
// 10us/dispatch + kernel work. 5->3 dispatches. Block-range fusion is the
// SAME pattern verified in r8's ps_embed. Blocks:
//   [0,240): gram (r4-verified body; chunk=bid%80, pair=bid/80)
//   [240,632): ps — 16 waves/block, one (b,s) per wave, ballot+shfl
//   [632,1032): embed — 1 f32x4 per thread, per-block partial -> embPart
// gram blocks first (longest). VGPR=64/LDS 73.8KB -> 2 blocks/CU, so
// ps/embed blocks co-reside with gram blocks and fill its barrier stalls.
// Block 0 also zeroes the fence-counter used by dispatch 3 (stream-ordered).
// ---------------------------------------------------------------------------
__global__ __launch_bounds__(1024) void mega_kernel(
    const float* __restrict__ s0, const float* __restrict__ s1, const float* __restrict__ s2,
    const float* __restrict__ t0, const float* __restrict__ t1, const float* __restrict__ t2,
    const float* __restrict__ batch,
    const f32x4* __restrict__ hs, const f32x4* __restrict__ ht,
    const f32x4* __restrict__ ds, const f32x4* __restrict__ dt,
    unsigned short* __restrict__ part,
    float* __restrict__ pc, float* __restrict__ pt, float* __restrict__ pe,
    float* __restrict__ aarr, float* __restrict__ embPart,
    unsigned int* __restrict__ counter) {
  __shared__ unsigned int pan[2][2][NB * LROWU];   // 73728 B (gram)
  __shared__ float wsum[16];                       // embed cross-wave

  const int bid = blockIdx.x;
  const int tid = threadIdx.x;

  if (bid == 0 && tid == 0) *counter = 0;          // for dispatch 3

  if (bid < GRAM_BLOCKS) {
    // ---------------- gram (verified r4 body) ----------------
    const int chunk = bid % KCHUNKS;
    const int pair = bid / KCHUNKS;
    const float* S  = (pair == 0) ? s0 : ((pair == 1) ? s1 : s2);
    const float* Tm = (pair == 0) ? t0 : ((pair == 1) ? t1 : t2);

    const int wave = tid >> 6, lane = tid & 63;
    const int wrow = wave >> 2, wcol = wave & 3;
    const int l15 = lane & 15, quad = lane >> 4;

    f32x4 aXY[2][2], aXX[2][2], aYY[2][2];
#pragma unroll
    for (int i = 0; i < 2; i++)
#pragma unroll
      for (int j = 0; j < 2; j++) {
        aXY[i][j] = (f32x4){0.f, 0.f, 0.f, 0.f};
        aXX[i][j] = (f32x4){0.f, 0.f, 0.f, 0.f};
        aYY[i][j] = (f32x4){0.f, 0.f, 0.f, 0.f};
      }

    const int r0 = tid >> 4;
    const int kq = tid & 15;
    const size_t ro0 = (size_t)r0 * K_DIM;
    const size_t ro1 = (size_t)(r0 + 64) * K_DIM;
    const int kbase = chunk * KC;

    f32x4 A0, A1, A2, A3, B0, B1, B2, B3;

    issue_loads(S, Tm, ro0, ro1, kbase, kq, A0, A1, A2, A3);
    issue_loads(S, Tm, ro0, ro1, kbase + BK, kq, B0, B1, B2, B3);
    cvt_write(&pan[0][0][0], &pan[0][1][0], r0, kq, A0, A1, A2, A3);
    __syncthreads();

    for (int s2 = 0; s2 < NSTAGE; s2 += 2) {
      if (s2 + 2 < NSTAGE)
        issue_loads(S, Tm, ro0, ro1, kbase + (s2 + 2) * BK, kq, A0, A1, A2, A3);
      compute_stage(&pan[0][0][0], &pan[0][1][0], wrow, wcol, l15, quad, aXY, aXX, aYY);
      cvt_write(&pan[1][0][0], &pan[1][1][0], r0, kq, B0, B1, B2, B3);
      __syncthreads();

      if (s2 + 3 < NSTAGE)
        issue_loads(S, Tm, ro0, ro1, kbase + (s2 + 3) * BK, kq, B0, B1, B2, B3);
      compute_stage(&pan[1][0][0], &pan[1][1][0], wrow, wcol, l15, quad, aXY, aXX, aYY);
      if (s2 + 2 < NSTAGE) {
        cvt_write(&pan[0][0][0], &pan[0][1][0], r0, kq, A0, A1, A2, A3);
        __syncthreads();
      }
    }

#pragma unroll
    for (int kind = 0; kind < 3; kind++) {
      unsigned short* out = part + ((size_t)(pair * 3 + kind) * KCHUNKS + chunk) * GRAM_N;
#pragma unroll
      for (int ti = 0; ti < 2; ti++)
#pragma unroll
        for (int tj = 0; tj < 2; tj++) {
          const f32x4 v = (kind == 0) ? aXY[ti][tj] : ((kind == 1) ? aXX[ti][tj] : aYY[ti][tj]);
          const int col = wcol * 32 + tj * 16 + l15;
#pragma unroll
          for (int r = 0; r < 4; r++) {
            const int row = wrow * 32 + ti * 16 + quad * 4 + r;
            out[(size_t)row * NB + col] = f2bf_rn(v[r]);
          }
        }
    }
  } else if (bid < EMB_BASE) {
    // ---------------- ps gather (verified r8 body, 16 waves/block) --------
    const int w = (bid - PS_BASE) * 16 + (tid >> 6);   // 0..6271
    const int lane = tid & 63;
    const int b = w / S_DIM, s = w - b * S_DIM;
    const float* brow = batch + ((size_t)b * T_DIM + (s + 1)) * (2 * Q_DIM);

    int qv = 0; float dsv = 0.f; bool found = false;
#pragma unroll
    for (int c = 0; c < 4; c++) {
      const int base = c * 256 + lane * 4;             // coalesced f32x4
      const f32x4 d0 = *(const f32x4*)(brow + base);
      const f32x4 d1 = *(const f32x4*)(brow + Q_DIM + base);
#pragma unroll
      for (int j = 0; j < 4; j++)
        if (d0[j] + d1[j] > 0.5f) { qv = base + j; dsv = d0[j] - d1[j]; found = true; }
    }
    const unsigned long long m = __ballot(found);
    const int src = (m != 0ull) ? (__ffsll((unsigned long long)m) - 1) : 0;
    qv = __shfl(qv, src, 64);
    dsv = __shfl(dsv, src, 64);
    if (lane == 0) {
      const size_t off = ((size_t)b * T_DIM + s) * Q_DIM + qv;
      pc[w] = 2.0f * s0[off];   // 1/TEMP (s0 = lc, s1 = lt, s2 = le)
      pt[w] = 2.0f * s1[off];
      pe[w] = 2.0f * s2[off];
      aarr[w] = (m != 0ull && dsv > 0.0f) ? 1.0f : 0.0f;
    }
  } else {
    // ---------------- embed partial (verified r8 body, 1 elem/thread) -----
    const int eb = bid - EMB_BASE;                     // 0..399
    const int idx = eb * 1024 + tid;                   // covers 409600 exactly
    const f32x4 a = hs[idx] - ht[idx];
    const f32x4 b = ds[idx] - dt[idx];
    float sum = a[0]*a[0] + a[1]*a[1] + a[2]*a[2] + a[3]*a[3]
              + b[0]*b[0] + b[1]*b[1] + b[2]*b[2] + b[3]*b[3];
    for (int off = 32; off > 0; off >>= 1) sum += __shfl_down(sum, off, 64);
    const int lane = tid & 63, wv = tid >> 6;
    if (lane == 0) wsum[wv] = sum;
    __syncthreads();
    if (tid == 0) {
      float t = 0.f;
#pragma unroll
      for (int i = 0; i < 16; i++) t += wsum[i];
      embPart[eb] = t;
    }
  }
}

// ---------------------------------------------------------------------------
// Dispatch 2: reduce bf16 K-chunk partials -> gram[9][128][128] (f32)
// ---------------------------------------------------------------------------
__global__ __launch_bounds__(256) void gram_reduce_kernel(
    const unsigned short* __restrict__ part, float* __restrict__ gram) {
  const int idx = blockIdx.x * 256 + threadIdx.x;   // < 9*16384
  const int g = idx >> 14;
  const int cell = idx & (GRAM_N - 1);
  const unsigned short* p = part + (size_t)g * KCHUNKS * GRAM_N + cell;
  float s = 0.f;
#pragma unroll
  for (int c = 0; c < KCHUNKS; c++) s += bf2f(p[(size_t)c * GRAM_N]);
  gram[idx] = s;
}

// ---------------------------------------------------------------------------
// Dispatch 3: Sinkhorn (9 blocks) + fence-counter last-block CE/combine.
// Sinkhorn math unchanged (verified 7x). After each block writes its kdpart:
// __threadfence(); atomicAdd(counter); the block observing ticket==8 (all 9
// kdpart written & fenced) runs the CE + final combine (r8-verified math),
// then resets counter for the next graph replay. No spin, no dispatch-order
// assumption. LDS is a union: sinkhorn state 70.7KB / ce state 101.4KB.
// ---------------------------------------------------------------------------
union SHU {
  struct {
    float CL[NB * CPAD];     // 67584 B
    float h[2][NB];          // pot0 / pot1
    float nx[NB], ny[NB];
    float red[256];
  } s;
  struct {
    float sx[4][NB][S_DIM];  // 100352 B: 0:pt 1:pc 2:pe 3:a
    float red[256], rede[256];
  } c;
};

__global__ __launch_bounds__(256, 1) void sinkhorn_ce_kernel(
    const float* __restrict__ gram, float* __restrict__ kdpart,
    const float* __restrict__ pcb, const float* __restrict__ ptb,
    const float* __restrict__ peb, const float* __restrict__ ab,
    const float* __restrict__ embPart, unsigned int* __restrict__ counter,
    float* __restrict__ outp) {
  __shared__ SHU sh;
  __shared__ int ticket;

  const int pair = blockIdx.x, kind = blockIdx.y;
  const float* Gxy = gram + (size_t)(3 * pair + 0) * GRAM_N;
  const float* Gxx = gram + (size_t)(3 * pair + 1) * GRAM_N;
  const float* Gyy = gram + (size_t)(3 * pair + 2) * GRAM_N;

  const int tid = threadIdx.x;
  if (tid < NB) {
    sh.s.nx[tid] = Gxx[tid * (NB + 1)];
    sh.s.ny[tid] = Gyy[tid * (NB + 1)];
    sh.s.h[0][tid] = 0.f;
    sh.s.h[1][tid] = 0.f;
  }
  __syncthreads();

  const float* G  = (kind == 0) ? Gxy : ((kind == 1) ? Gxx : Gyy);
  const float* rn = (kind == 2) ? sh.s.ny : sh.s.nx;
  const float* cn = (kind == 1) ? sh.s.nx : sh.s.ny;
  for (int idx = tid; idx < GRAM_N; idx += 256) {
    const int i = idx >> 7, j = idx & 127;
    sh.s.CL[i * CPAD + j] = 2.0f * fmaxf(rn[i] + cn[j] - 2.0f * G[idx], 0.0f);
  }
  __syncthreads();

  const float rho = 250000.0f;
  const float AL = -4.852030263919617f;     // -log(128)
  const float LOG2E = 1.4426950408889634f;
  const float LN2 = 0.6931471805599453f;
  const int grp = tid >> 7;
  const int i = tid & 127;
  const bool active = (kind == 0) || (grp == 0);
  const bool colread = (kind == 0) && (grp == 1);

  f32x4 crow[32];
  if (active) {
    if (colread) {
#pragma unroll
      for (int jj = 0; jj < 32; jj++) {
        f32x4 v;
        v[0] = sh.s.CL[(4 * jj + 0) * CPAD + i];
        v[1] = sh.s.CL[(4 * jj + 1) * CPAD + i];
        v[2] = sh.s.CL[(4 * jj + 2) * CPAD + i];
        v[3] = sh.s.CL[(4 * jj + 3) * CPAD + i];
        crow[jj] = v;
      }
    } else {
#pragma unroll
      for (int jj = 0; jj < 32; jj++)
        crow[jj] = *(const f32x4*)&sh.s.CL[i * CPAD + 4 * jj];
    }
  }

  float eps = 1.0f;
  for (int it = 0; it < 9; it++) {
    if (it == 8) eps = 2.5e-5f;             // BLUR^P
    const float inv_eps = 1.0f / eps;
    const float damp = 1.0f / (1.0f + eps / rho);
    const float ebl = eps * AL;

    float newp = 0.f;
    if (active) {
      const int hsel = (kind == 0 && grp == 0) ? 1 : 0;
      const f32x4* h = (const f32x4*)sh.s.h[hsel];
      f32x4 m4 = (f32x4){-3.0e38f, -3.0e38f, -3.0e38f, -3.0e38f};
#pragma unroll
      for (int jj = 0; jj < 32; jj++) {
        const f32x4 u = h[jj] - crow[jj];
        m4[0] = fmaxf(m4[0], u[0]); m4[1] = fmaxf(m4[1], u[1]);
        m4[2] = fmaxf(m4[2], u[2]); m4[3] = fmaxf(m4[3], u[3]);
      }
      const float m = fmaxf(fmaxf(m4[0], m4[1]), fmaxf(m4[2], m4[3]));
      const float k = inv_eps * LOG2E;
      f32x4 s4 = (f32x4){0.f, 0.f, 0.f, 0.f};
#pragma unroll
      for (int jj = 0; jj < 32; jj++) {
        const f32x4 u = h[jj] - crow[jj];
        s4[0] += __builtin_exp2f((u[0] - m) * k);
        s4[1] += __builtin_exp2f((u[1] - m) * k);
        s4[2] += __builtin_exp2f((u[2] - m) * k);
        s4[3] += __builtin_exp2f((u[3] - m) * k);
      }
      const float Ssum = (s4[0] + s4[1]) + (s4[2] + s4[3]);   // >= 1
      const float sm = -(m + ebl + eps * (LN2 * __log2f(Ssum)));
      if (kind == 0) newp = damp * sm;
      else           newp = 0.5f * (sh.s.h[0][i] + damp * sm);
    }
    __syncthreads();                        // all reads of h done
    if (active) sh.s.h[grp][i] = newp;
    __syncthreads();                        // new pots visible
    eps *= 0.25f;                           // SCALING^P
  }

  float v = 0.f;
  if (kind == 0) {
    v = (grp == 0) ? -__expf(-sh.s.h[0][i] / rho)
                   : -__expf(-sh.s.h[1][i] / rho);
  } else if (grp == 0) {
    v = __expf(-sh.s.h[0][i] / rho);
  }
  sh.s.red[tid] = v;
  __syncthreads();
  for (int st = 128; st > 0; st >>= 1) {
    if (tid < st) sh.s.red[tid] += sh.s.red[tid + st];
    __syncthreads();
  }
  if (tid == 0) kdpart[pair * 3 + kind] = sh.s.red[0];

  // ---- fence-counter: last block runs CE + combine ----
  __threadfence();                          // publish kdpart device-wide
  __syncthreads();
  if (tid == 0) ticket = (int)atomicAdd(counter, 1u);
  __syncthreads();
  if (ticket != 8) return;
  __threadfence();                          // acquire all 9 kdpart

  // stage CE inputs into (reused) LDS
  for (int idx = tid; idx < NB * S_DIM; idx += 256) {
    const int b = idx / S_DIM, s = idx - b * S_DIM;
    sh.c.sx[0][b][s] = ptb[idx];
    sh.c.sx[1][b][s] = pcb[idx];
    sh.c.sx[2][b][s] = peb[idx];
    sh.c.sx[3][b][s] = ab[idx];
  }
  float esum = 0.f;
  for (int j = tid; j < EMB_BLOCKS; j += 256) esum += embPart[j];
  __syncthreads();

  float loss = 0.f;
  if (tid < NB) {
    const int b = tid;
    int last = -1;
    for (int s = 0; s < S_DIM; s++)
      if (sh.c.sx[1][b][s] > 0.0f) last = s;
    const int L = (last >= 0) ? (last + 1) : S_DIM;
#pragma unroll
    for (int k = 0; k < 3; k++) {
      float m = -3.0e38f;
      for (int s = 0; s < L; s++) m = fmaxf(m, sh.c.sx[k][b][s]);
      float sum = 0.f;
      for (int s = 0; s < L; s++) sum += __expf(sh.c.sx[k][b][s] - m);
      const float lse = m + __logf(sum);
      float l = 0.f;
      for (int s = 0; s < L; s++) l += sh.c.sx[3][b][s] * (sh.c.sx[k][b][s] - lse);
      loss -= l;
    }
  }
  sh.c.red[tid] = loss;
  sh.c.rede[tid] = esum;
  __syncthreads();
  for (int st = 128; st > 0; st >>= 1) {
    if (tid < st) { sh.c.red[tid] += sh.c.red[tid + st]; sh.c.rede[tid] += sh.c.rede[tid + st]; }
    __syncthreads();
  }
  if (tid == 0) {
    float kd = 0.f;
    for (int k = 0; k < 9; k++) kd += kdpart[k];
    // w * a_w = (rho + eps_final/2) / 128 ; DIST_W = 0.01
    outp[0] = sh.c.red[0] + 0.01f * (250000.0000125f / 128.0f) * kd + 0.5f * sh.c.rede[0];
    *counter = 0;                           // reset for next graph replay
  }
}

// ---------------------------------------------------------------------------
extern "C" void kernel_launch(void* const* d_in, const int* in_sizes, int n_in,
                              void* d_out, int out_size, void* d_ws, size_t ws_size,
                              hipStream_t stream) {
  const float* lc    = (const float*)d_in[0];
  const float* lt    = (const float*)d_in[1];
  const float* le    = (const float*)d_in[2];
  const float* ltc   = (const float*)d_in[3];
  const float* ltt   = (const float*)d_in[4];
  const float* lte   = (const float*)d_in[5];
  const float* ohs   = (const float*)d_in[6];
  const float* oht   = (const float*)d_in[7];
  const float* ods   = (const float*)d_in[8];
  const float* odt   = (const float*)d_in[9];
  const float* batch = (const float*)d_in[10];

  unsigned short* part = (unsigned short*)d_ws;        // 9*80*16384*2B = 23.6 MB
  float* gram = (float*)(part + (size_t)9 * KCHUNKS * GRAM_N);  // 9*16384 f32
  float* pcb  = gram + 9 * GRAM_N;                     // 128*49 each
  float* ptb  = pcb + NB * S_DIM;
  float* peb  = ptb + NB * S_DIM;
  float* ab   = peb + NB * S_DIM;
  float* kdp  = ab + NB * S_DIM;                       // 9
  float* embp = kdp + 9;                               // 400
  unsigned int* counter = (unsigned int*)(embp + EMB_BLOCKS);   // 1

  // Dispatch 1: gram + ps + embed (+ counter zero)
  mega_kernel<<<TOTAL_BLOCKS, 1024, 0, stream>>>(
      lc, lt, le, ltc, ltt, lte, batch,
      (const f32x4*)ohs, (const f32x4*)oht, (const f32x4*)ods, (const f32x4*)odt,
      part, pcb, ptb, peb, ab, embp, counter);

  // Dispatch 2: partial reduce
  gram_reduce_kernel<<<(9 * GRAM_N) / 256, 256, 0, stream>>>(part, gram);

  // Dispatch 3: sinkhorn chains + last-block CE/combine
  sinkhorn_ce_kernel<<<dim3(3, 3), 256, 0, stream>>>(
      gram, kdp, pcb, ptb, peb, ab, embp, counter, (float*)d_out);
}